// Round 3
// baseline (447.003 us; speedup 1.0000x reference)
//
#include <hip/hip_runtime.h>

// Cost-volume builder:
// out[b, c2, d, h, w] with shape (4, 64, 48, 64, 128) fp32
//   c2 <  32: (w >= d) ? left [b, c2,    h, w    ] : 0
//   c2 >= 32: (w >= d) ? right[b, c2-32, h, w - d] : 0
//
// Write-bound: 402.7 MB out vs 8 MB in. Timed region = re-poison fill
// (~255 us, 1.6 GB @ 6.3 TB/s) + this kernel.
//
// History: R3 (1 store/thread, 98K blocks) kernel ~167 us (2.4 TB/s).
// R4 (48 stores/thread walking d, 2048 blocks) ~136 us (3.0 TB/s).
// R5 (hoisted loads, plain stores) ~136 us -- NEUTRAL, killing the vmcnt
// theory and the nt-store theory.
//
// R6 theory: instantaneous write-window locality. The 6.3 TB/s fill kernel
// grid-strides linearly -- the chip's outstanding writes form ONE contiguous
// sliding window. R4/R5 had 2048 blocks each striding 8 KB inside its own
// 1.5 MB region: 2048 scattered chunks across 403 MB at any instant -> DRAM
// row thrash at the memory controllers. R6 mimics the fill exactly:
// 1024 blocks x 256 threads grid-stride the output in LINEAR order (4 MB
// sliding window, 96 iterations), decoding (bc,d,h,k0) from the linear index.
// Slab size 2048 float4 is pow2 -> decode is one magic-mul div + shifts, and
// a wave never straddles a slab, so d and the left/right branch are
// wave-uniform. Right half: d=4q+s -> two aligned loads + uniform switch on s;
// zeroing reads past the row start reproduces the (w>=d) mask exactly.

#define BB 4
#define CC 32
#define HH 64
#define WW 128
#define DD 48

#define SLAB4 (HH * WW / 4)          // 2048 float4 per (bc,d) slab (pow2)
#define BC4   (DD * SLAB4)           // 98304 float4 per bc
#define N4    (BB * 2 * CC * BC4)    // 25165824 float4 total
#define NBLK  1024
#define NTHR  (NBLK * 256)           // 262144 -> exactly 96 iterations
#define ITERS (N4 / NTHR)            // 96, no tail

typedef float vfloat4 __attribute__((ext_vector_type(4)));

__global__ __launch_bounds__(256) void cost_kernel(
    const float* __restrict__ left,
    const float* __restrict__ right,
    float* __restrict__ out)
{
    int idx = blockIdx.x * 256 + threadIdx.x;
    vfloat4* __restrict__ out4 = reinterpret_cast<vfloat4*>(out);

    #pragma unroll 4
    for (int it = 0; it < ITERS; ++it, idx += NTHR) {
        // ---- decode linear float4 index -> (bc, d, p, h, k0) ----
        const int bc = idx / BC4;            // magic-mul, 2 VALU
        const int r1 = idx - bc * BC4;
        const int d  = r1 >> 11;             // SLAB4 = 2^11
        const int p  = idx & (SLAB4 - 1);    // BC4 is a multiple of SLAB4
        const int h  = p >> 5;               // W/4 = 32 float4 per row
        const int k0 = p & 31;
        const int w0 = k0 * 4;

        const int  b        = bc >> 6;
        const bool is_right = (bc & 32) != 0;   // c2 = bc & 63; right <=> c2 >= 32
        const int  c        = bc & 31;
        const float* __restrict__ src = is_right ? right : left;
        const vfloat4* __restrict__ row4 = reinterpret_cast<const vfloat4*>(
            src + (((size_t)(b * CC + c) * HH + h) * WW));

        vfloat4 o;
        if (!is_right) {
            // load + (w >= d) mask; d is wave-uniform, only d > w0 lanes mask
            const vfloat4 lv = row4[k0];
            o.x = (w0 + 0 >= d) ? lv.x : 0.0f;
            o.y = (w0 + 1 >= d) ? lv.y : 0.0f;
            o.z = (w0 + 2 >= d) ? lv.z : 0.0f;
            o.w = (w0 + 3 >= d) ? lv.w : 0.0f;
        } else {
            // window right[w0-d .. w0+3-d]: d = 4q + s (both wave-uniform);
            // sources row4[k0-q] (Bv) and row4[k0-q-1] (Av); zero past row
            // start IS the (w >= d) mask.
            const int q = d >> 2;
            const int s = d & 3;
            const int j = k0 - q;
            vfloat4 Bv = (vfloat4)(0.0f);
            vfloat4 Av = (vfloat4)(0.0f);
            if (j >= 0) Bv = row4[j];
            if (j >= 1) Av = row4[j - 1];
            switch (s) {   // wave-uniform branch, static shuffles
                case 0:  o = Bv; break;
                case 1:  o.x = Av.w; o.y = Bv.x; o.z = Bv.y; o.w = Bv.z; break;
                case 2:  o.x = Av.z; o.y = Av.w; o.z = Bv.x; o.w = Bv.y; break;
                default: o.x = Av.y; o.y = Av.z; o.z = Av.w; o.w = Bv.x; break;
            }
        }

        out4[idx] = o;   // linear, chip-wide contiguous sliding window
    }
}

extern "C" void kernel_launch(void* const* d_in, const int* in_sizes, int n_in,
                              void* d_out, int out_size, void* d_ws, size_t ws_size,
                              hipStream_t stream)
{
    const float* left  = (const float*)d_in[0];
    const float* right = (const float*)d_in[1];
    float* out = (float*)d_out;

    cost_kernel<<<dim3(NBLK), dim3(256), 0, stream>>>(left, right, out);
}

// Round 4
// 390.606 us; speedup vs baseline: 1.1444x; 1.1444x over previous
//
#include <hip/hip_runtime.h>

// Cost-volume builder:
// out[b, c2, d, h, w] with shape (4, 64, 48, 64, 128) fp32
//   c2 <  32: (w >= d) ? left [b, c2,    h, w    ] : 0
//   c2 >= 32: (w >= d) ? right[b, c2-32, h, w - d] : 0
//
// Write-bound: 402.7 MB out vs 8 MB in. Timed region = re-poison fill
// (~255 us, 1.6 GB @ 6.3 TB/s) + this kernel.
//
// History: R3 (1 store/thread) kernel ~167 us. R4 (d-walk, 48 stores/thread)
// ~136 us (3.0 TB/s). R5 (loads hoisted, plain stores) ~136 -- nt and vmcnt
// theories dead. R6 (linear grid-stride + per-store decode/loads) ~192 --
// REGRESSION: dependent load chain before every store + window smearing.
//
// R7 = R5 body + XCD-contiguous write mapping. In R5's grid, bid%8 (= XCD on
// round-robin dispatch) selected the p-chunk, so each XCD wrote 4KB fragments
// every 32KB across the whole 403MB -- 8 maximally-fragmented write-back
// streams interleaving at the controllers. The 6.3 TB/s fill, by contrast,
// emits one clean sequential stream per XCD. R7 remaps so XCD k owns four
// contiguous 12.6MB chunks (2 left + 2 right, keeping load balance):
//   flat -> xcd = flat&7, idx = flat>>3, chunk_sel = idx>>6, r = idx&63
//   chunk_id = chunk_sel*8 + xcd  (0..31), bc = chunk_id*8 + (r>>3), x = r&7
// Consecutive same-XCD blocks (stride-8 flat ids) walk p-then-bc within the
// chunk: dense contiguous per-XCD write-back runs. Kernel body unchanged.

#define BB 4
#define CC 32
#define HH 64
#define WW 128
#define DD 48

typedef float vfloat4 __attribute__((ext_vector_type(4)));

__global__ __launch_bounds__(256) void cost_kernel(
    const float* __restrict__ left,
    const float* __restrict__ right,
    float* __restrict__ out)
{
    // 1-D grid of 2048 blocks; XCD-contiguous work mapping.
    const int flat      = blockIdx.x;
    const int xcd       = flat & 7;
    const int idx_in    = flat >> 3;        // 0..255
    const int chunk_sel = idx_in >> 6;      // 0..3  (2 left + 2 right per XCD)
    const int r         = idx_in & 63;      // 0..63 within chunk
    const int chunk_id  = chunk_sel * 8 + xcd;      // 0..31
    const int bc        = chunk_id * 8 + (r >> 3);  // 0..255
    const int x         = r & 7;                    // p-chunk within slab

    const int p  = x * 256 + threadIdx.x;   // float4 index within (h,w) plane
    const int b  = bc >> 6;
    const int c2 = bc & 63;
    const int h  = p >> 5;                  // W/4 = 32 float4 per row
    const int k0 = p & 31;                  // float4 column within row
    const int w0 = k0 * 4;                  // starting w of this float4

    const bool is_right = (c2 >= CC);       // uniform per block
    const int  c        = is_right ? (c2 - CC) : c2;
    const float* __restrict__ src = is_right ? right : left;
    const vfloat4* __restrict__ row4 =
        reinterpret_cast<const vfloat4*>(src + ((((size_t)b * CC + c) * HH + h) * WW));

    const int stride4 = HH * WW / 4;        // 2048 float4 per d-slab
    vfloat4* __restrict__ out4 = reinterpret_cast<vfloat4*>(out)
                               + (size_t)bc * DD * stride4 + p;

    if (!is_right) {
        // One load, 48 stores; load is oldest vmcnt entry, stores never gate.
        const vfloat4 lv = row4[k0];
        #pragma unroll
        for (int d = 0; d < DD; ++d) {
            vfloat4 o;
            o.x = (w0 + 0 >= d) ? lv.x : 0.0f;
            o.y = (w0 + 1 >= d) ? lv.y : 0.0f;
            o.z = (w0 + 2 >= d) ? lv.z : 0.0f;
            o.w = (w0 + 3 >= d) ? lv.w : 0.0f;
            out4[(size_t)d * stride4] = o;
        }
    } else {
        // Preload every source float4 this thread will ever need (r[g] covers
        // disparity group g = d/4). rr[g] = 0 once k0-g < 0 -- this reproduces
        // the (w >= d) mask exactly, no mask instructions.
        vfloat4 rr[DD / 4 + 1];
        #pragma unroll
        for (int g = 0; g <= DD / 4; ++g) {
            rr[g] = (vfloat4)(0.0f);
            if (k0 - g >= 0) rr[g] = row4[k0 - g];
        }

        // 48 back-to-back stores, windows built purely in registers with
        // static indices (stays in VGPRs after full unroll).
        #pragma unroll
        for (int g = 0; g < DD / 4; ++g) {
            const vfloat4 b4 = rr[g];
            const vfloat4 a4 = rr[g + 1];

            const vfloat4 o0 = b4;
            vfloat4 o1; o1.x = a4.w; o1.y = b4.x; o1.z = b4.y; o1.w = b4.z;
            vfloat4 o2; o2.x = a4.z; o2.y = a4.w; o2.z = b4.x; o2.w = b4.y;
            vfloat4 o3; o3.x = a4.y; o3.y = a4.z; o3.z = a4.w; o3.w = b4.x;

            out4[(size_t)(4 * g + 0) * stride4] = o0;
            out4[(size_t)(4 * g + 1) * stride4] = o1;
            out4[(size_t)(4 * g + 2) * stride4] = o2;
            out4[(size_t)(4 * g + 3) * stride4] = o3;
        }
    }
}

extern "C" void kernel_launch(void* const* d_in, const int* in_sizes, int n_in,
                              void* d_out, int out_size, void* d_ws, size_t ws_size,
                              hipStream_t stream)
{
    const float* left  = (const float*)d_in[0];
    const float* right = (const float*)d_in[1];
    float* out = (float*)d_out;

    cost_kernel<<<dim3(2048), dim3(256), 0, stream>>>(left, right, out);
}